// Round 4
// baseline (145.653 us; speedup 1.0000x reference)
//
#include <hip/hip_runtime.h>
#include <math.h>
#include <limits.h>
#include <stdint.h>

namespace {
constexpr int G = 16;    // num_graphs
constexpr int N = 2048;  // num_nodes
constexpr int K = 16;    // k_neighs
constexpr int C = 20;    // candidates per side (K + diag exclusion + tie slack)
typedef float floatx4 __attribute__((ext_vector_type(4)));
}

// 2*G blocks, 1 wave each. Block b: g = b>>1, side = b&1 (0 = largest t, 1 = smallest t).
// Emits candidate indices in exact (value, then lower index) order — lax.top_k tie-break.
__global__ void topk_kernel(const float* __restrict__ emb_t,
                            int* __restrict__ candidx /* [2*G][C] */) {
    __shared__ float sv[N];
    const int g = blockIdx.x >> 1;
    const int side = blockIdx.x & 1;
    const int lane = threadIdx.x;            // 64 = one wave
    const float* t = emb_t + g * N;
    const float sgn = side ? -1.f : 1.f;     // negate for min side -> always argmax

    for (int m = 0; m < N / 64; ++m) sv[lane + 64 * m] = sgn * t[lane + 64 * m];
    __syncthreads();

    for (int p = 0; p < C; ++p) {
        float bv = -INFINITY; int bi = INT_MAX;
        for (int m = 0; m < N / 64; ++m) {
            const int idx = lane + 64 * m;
            const float v = sv[idx];
            if (v > bv || (v == bv && idx < bi)) { bv = v; bi = idx; }
        }
        #pragma unroll
        for (int off = 32; off >= 1; off >>= 1) {
            const float ov = __shfl_xor(bv, off);
            const int   oi = __shfl_xor(bi, off);
            if (ov > bv || (ov == bv && oi < bi)) { bv = ov; bi = oi; }
        }
        if (lane == 0) { candidx[blockIdx.x * C + p] = bi; sv[bi] = -INFINITY; }
        __syncthreads();
    }
}

// Per-row selection logic shared by mask_kernel and the fallback fill_kernel.
// Returns this lane's 32-bit membership word (lane l owns columns [32l, 32l+32)).
__device__ __forceinline__ unsigned row_word(const float* __restrict__ emb_s,
                                             const float* __restrict__ emb_t,
                                             const int* __restrict__ candidx,
                                             int row, int lane) {
    const int g = row >> 11;             // N = 2048
    const int i = row & (N - 1);
    const float s = emb_s[row];

    int idx = INT_MAX;
    bool sel = false;
    if (s != 0.0f) {
        const int* list = candidx + (g * 2 + (s < 0.0f)) * C;
        float p = -INFINITY;
        if (lane < C) {
            idx = list[lane];
            p = s * emb_t[g * N + idx];          // same rounding as reference adj
            if (idx == i) { p = -INFINITY; idx = INT_MAX; }  // exclude diagonal
        }
        // exact top_k rank among candidates: (value desc, index asc)
        int rank = 0;
        for (int c = 0; c < C; ++c) {
            const float pc = __shfl(p, c);
            const int   ic = __shfl(idx, c);
            if (pc > p || (pc == p && ic < idx)) ++rank;
        }
        sel = (lane < C) && (rank < K) && (idx != INT_MAX);
    } else {
        // s == +/-0: all products are +/-0 (compare-equal) -> lowest K indices, skip i
        if (lane < K) {
            const int pos = (i < K + 1) ? i : (K + 1);
            idx = (lane < pos) ? lane : lane + 1;
            sel = true;
        }
    }

    unsigned word = 0;
    for (int c = 0; c < C; ++c) {
        const int ic = __shfl(idx, c);
        const int sc = __shfl((int)sel, c);
        if (sc && (ic >> 5) == lane) word |= 1u << (ic & 31);
    }
    return word;
}

// Mask build: one wave per row (grid-stride), writes 64 words (256 B) coalesced.
__global__ __launch_bounds__(256) void mask_kernel(
    const float* __restrict__ emb_s,
    const float* __restrict__ emb_t,
    const int* __restrict__ candidx,
    uint32_t* __restrict__ mask)
{
    const int lane = threadIdx.x & 63;
    const int wid = blockIdx.x * 4 + (threadIdx.x >> 6);
    const int nw = gridDim.x * 4;
    for (int row = wid; row < G * N; row += nw) {
        mask[(size_t)row * 64 + lane] = row_word(emb_s, emb_t, candidx, row, lane);
    }
}

// Pure write stream, memset-shaped: per float4, one broadcast dword mask load
// (8 lanes share a word, L1 hit) + bit->float unpack + one regular dwordx4 store.
__global__ __launch_bounds__(256) void stream_kernel(
    const uint32_t* __restrict__ mask,
    floatx4* __restrict__ out)
{
    const size_t total = (size_t)G * N * (N / 4);      // 16,777,216 float4s
    const size_t stride = (size_t)gridDim.x * 256;
    size_t q = (size_t)blockIdx.x * 256 + threadIdx.x;
    #pragma unroll 4
    for (; q < total; q += stride) {
        const unsigned w = mask[q >> 3];               // word covers 8 float4s
        const int b0 = ((int)q & 7) * 4;
        floatx4 v;
        v.x = (float)((w >> (b0 + 0)) & 1u);
        v.y = (float)((w >> (b0 + 1)) & 1u);
        v.z = (float)((w >> (b0 + 2)) & 1u);
        v.w = (float)((w >> (b0 + 3)) & 1u);
        out[q] = v;
    }
}

// Fallback (proven R2 path) if the workspace is too small for the mask array.
__global__ __launch_bounds__(256) void fill_kernel(
    const float* __restrict__ emb_s,
    const float* __restrict__ emb_t,
    const int* __restrict__ candidx,
    float* __restrict__ out)
{
    const int lane = threadIdx.x & 63;
    const int wid = blockIdx.x * 4 + (threadIdx.x >> 6);
    const int nw = gridDim.x * 4;
    for (int row = wid; row < G * N; row += nw) {
        const unsigned word = row_word(emb_s, emb_t, candidx, row, lane);
        float* rowp = out + (size_t)row * N;
        #pragma unroll
        for (int c = 0; c < 8; ++c) {
            const unsigned w = (unsigned)__shfl((int)word, c * 8 + (lane >> 3));
            const int b0 = (lane & 7) * 4;
            floatx4 v;
            v.x = (float)((w >> (b0 + 0)) & 1u);
            v.y = (float)((w >> (b0 + 1)) & 1u);
            v.z = (float)((w >> (b0 + 2)) & 1u);
            v.w = (float)((w >> (b0 + 3)) & 1u);
            *(reinterpret_cast<floatx4*>(rowp) + c * 64 + lane) = v;
        }
    }
}

extern "C" void kernel_launch(void* const* d_in, const int* in_sizes, int n_in,
                              void* d_out, int out_size, void* d_ws, size_t ws_size,
                              hipStream_t stream) {
    const float* emb_s = (const float*)d_in[0];   // (G, N, 1) f32
    const float* emb_t = (const float*)d_in[1];   // (G, 1, N) f32

    int* candidx = (int*)d_ws;                    // [2*G][C] ints (2560 B)
    const size_t maskOff = 4096;
    const size_t needed = maskOff + (size_t)G * N * 64 * sizeof(uint32_t);  // ~8.4 MB

    topk_kernel<<<2 * G, 64, 0, stream>>>(emb_t, candidx);

    if (ws_size >= needed) {
        uint32_t* mask = (uint32_t*)((char*)d_ws + maskOff);
        mask_kernel<<<512, 256, 0, stream>>>(emb_s, emb_t, candidx, mask);
        stream_kernel<<<2048, 256, 0, stream>>>(mask, (floatx4*)d_out);
    } else {
        fill_kernel<<<1024, 256, 0, stream>>>(emb_s, emb_t, candidx, (float*)d_out);
    }
}